// Round 5
// baseline (886.318 us; speedup 1.0000x reference)
//
#include <hip/hip_runtime.h>
#include <math.h>

// XMIX v5 — narrow paths (b1, v1, wf) moved to exact fp32 VALU; wide MFMA
// (h1 -> w1) unchanged from rounds 3/4 (A-side bf16 hi+lo split = ~fp32).
//
// MFMA 16x16x32 bf16 layouts (learn_hip-verified):
//   A: lane L holds A[m=L&15][k=(L>>4)*8+j]
//   B: lane L holds B[k=(L>>4)*8+j][n=L&15]
//   C/D: lane L reg r holds D[row=(L>>4)*4+r][col=L&15]

typedef __attribute__((ext_vector_type(8))) short bfrag8;
typedef __attribute__((ext_vector_type(4))) float f32x4;

#define BTOT 32768
#define TB 32
#define NBLK (BTOT / TB)

// ws: G3: B3[512x576]=W1a|Wfa|Wb1|Wv1 (36 nt x 16 kt); G4: B4[256x288]=W1b|Wfb (18 nt x 8 kt)
// (narrow ntiles 32-35 of G3 and 16-17 of G4 are prepped but no longer consumed)
#define FRAG_G3 0
#define FRAG_G4 36864
#define NFRAG   46080   // * 16B = 737280 B (proven available)

__device__ __forceinline__ short f2bf(float x) {
    unsigned u = __builtin_bit_cast(unsigned, x);
    u += 0x7fffu + ((u >> 16) & 1u);   // RNE
    return (short)(u >> 16);
}
__device__ __forceinline__ float bf2f(short b) {
    unsigned u = ((unsigned)(unsigned short)b) << 16;
    return __builtin_bit_cast(float, u);
}

__global__ __launch_bounds__(256) void xmix_prep(
    const float* __restrict__ W1a,  const float* __restrict__ W1b,
    const float* __restrict__ Wfa,  const float* __restrict__ Wfb,
    const float* __restrict__ Wb1,  const float* __restrict__ Wv1,
    bfrag8* __restrict__ ws)
{
    const int gid = blockIdx.x * 256 + threadIdx.x;
    if (gid >= NFRAG) return;
    const int lane = gid & 63;
    const int nloc = lane & 15;
    const int kq = (lane >> 4) * 8;
    float vals[8];

    if (gid < FRAG_G4) {            // G3
        const int tile = gid >> 6;
        const int ntile = tile >> 4, ktile = tile & 15;
        const int n = ntile * 16 + nloc;
        const int kb = ktile * 32 + kq;
        #pragma unroll
        for (int j = 0; j < 8; j++) {
            const int k = kb + j;
            float v;
            if (n < 256)      v = W1a[k * 256 + n];
            else if (n < 512) v = Wfa[k * 256 + (n - 256)];
            else if (n < 544) v = Wb1[k * 32 + (n - 512)];
            else              v = Wv1[k * 32 + (n - 544)];
            vals[j] = v;
        }
    } else {                        // G4
        const int tile = (gid - FRAG_G4) >> 6;
        const int ntile = tile >> 3, ktile = tile & 7;
        const int n = ntile * 16 + nloc;
        const int kb = ktile * 32 + kq;
        #pragma unroll
        for (int j = 0; j < 8; j++) {
            const int k = kb + j;
            vals[j] = (n < 256) ? W1b[k * 256 + n] : Wfb[k * 32 + (n - 256)];
        }
    }
    bfrag8 p;
    #pragma unroll
    for (int j = 0; j < 8; j++) p[j] = f2bf(vals[j]);
    ws[gid] = p;
}

__global__ __launch_bounds__(256, 1) void xmix_main(
    const float* __restrict__ agent_qs,
    const float* __restrict__ states,
    const float* __restrict__ W_tok, const float* __restrict__ b_tok,
    const float* __restrict__ W_yfc, const float* __restrict__ b_yfc,
    const float* __restrict__ b1a,  const float* __restrict__ b1b,
    const float* __restrict__ bfa,  const float* __restrict__ bfb,
    const float* __restrict__ bb1,  const float* __restrict__ bv1,
    const float* __restrict__ Wb1,  const float* __restrict__ Wv1,
    const float* __restrict__ Wfb,
    const float* __restrict__ Wv2,  const float* __restrict__ bv2,
    const bfrag8* __restrict__ wf_all,
    float* __restrict__ out)
{
    // R0 region 4352 chunks (69632 B):
    //   phase A:  S fp32 padded, sample stride 544 floats (136 f4), agent stride 68
    //   GEMM3 in: A3 hi chunks [0,2048), A3 lo [2048,4096)
    //   GEMM4 in: A4a hi [0,1024), A4a lo [2048,3072),
    //             hf32 fp32: floats [4096,8192) = samples 0..15, [12288,16384) = 16..31
    //   epilogue: w1 fp32 = R0f floats [0,8192)
    __shared__ bfrag8 R0v[4352];
    __shared__ float wstage[4096]; // W_tok[64][32] | W_yfc[32][64]; later hid|tpr|wfs
    __shared__ float qs[32][8];
    __shared__ float b1s[32][32];
    __shared__ float v1s[32][32];
    __shared__ float bias3[512];   // b1a | bfa
    __shared__ float bias4[256];   // b1b
    __shared__ float bias1[32];
    __shared__ float bias2[64];
    __shared__ float wv2s[32];
    __shared__ float bfbs[32];

    short* R0s = (short*)R0v;
    float* R0f = (float*)R0v;
    float* wtokf = wstage;
    float* wyfcf = wstage + 2048;
    float (*hid)[32] = (float (*)[32])wstage;
    float (*tpr)[32] = (float (*)[32])(wstage + 1024);
    float (*wfs)[32] = (float (*)[32])(wstage + 2048);

    const int tid = threadIdx.x;
    const int w = tid >> 6, lane = tid & 63;
    const int quad = lane >> 4, nl = lane & 15;
    const int base = blockIdx.x * TB;

    // ---- phase 0 ----
    for (int i = tid; i < 512; i += 256) bias3[i] = (i < 256) ? b1a[i] : bfa[i - 256];
    if (tid < 256) bias4[tid] = b1b[tid];
    if (tid < 32)  bias1[tid] = b_tok[tid];
    if (tid < 64)  bias2[tid] = b_yfc[tid];
    if (tid < 32)  wv2s[tid] = Wv2[tid];
    if (tid < 32)  bfbs[tid] = bfb[tid];
    qs[tid >> 3][tid & 7] = agent_qs[base * 8 + tid];
    #pragma unroll
    for (int i = 0; i < 4; i++) {
        const int idx = tid + 256 * i;               // 0..1023
        ((float*)b1s)[idx] = bb1[idx & 31];          // seed with biases
        ((float*)v1s)[idx] = bv1[idx & 31];
    }
    #pragma unroll
    for (int i = 0; i < 16; i++) {
        const int idx = tid + 256 * i;
        wstage[idx] = (idx < 2048) ? W_tok[idx] : W_yfc[idx - 2048];
    }

    // ---- phase A: S fp32 -> LDS (padded) ----
    {
        float4* dst = (float4*)R0f;
        const float4* src = (const float4*)(states + (size_t)base * 512);
        #pragma unroll
        for (int i = 0; i < 16; i++) {
            const int g4 = tid + 256 * i;            // 0..4095
            const int s = g4 >> 7, rem = g4 & 127;
            const int a = rem >> 4, f4 = rem & 15;
            dst[s * 136 + a * 17 + f4] = src[g4];
        }
    }
    __syncthreads();

    // ---- P12 (fp32): E -> Y in registers; b1/v1 partials via LDS atomics ----
    float y[64];
    {
        const int s = tid >> 3, a = tid & 7;
        const float4* Srow = ((const float4*)R0f) + s * 136 + a * 17;
        float e[32];
        #pragma unroll
        for (int j = 0; j < 32; j++) e[j] = 0.f;
        #pragma unroll
        for (int f4 = 0; f4 < 16; f4++) {
            const float4 sv = Srow[f4];
            #pragma unroll
            for (int u = 0; u < 4; u++) {
                const float sf = (u == 0) ? sv.x : (u == 1) ? sv.y : (u == 2) ? sv.z : sv.w;
                const int f = f4 * 4 + u;
                #pragma unroll
                for (int j4 = 0; j4 < 8; j4++) {
                    const float4 wv = *(const float4*)&wtokf[f * 32 + j4 * 4];
                    e[j4 * 4 + 0] = fmaf(sf, wv.x, e[j4 * 4 + 0]);
                    e[j4 * 4 + 1] = fmaf(sf, wv.y, e[j4 * 4 + 1]);
                    e[j4 * 4 + 2] = fmaf(sf, wv.z, e[j4 * 4 + 2]);
                    e[j4 * 4 + 3] = fmaf(sf, wv.w, e[j4 * 4 + 3]);
                }
            }
        }
        #pragma unroll
        for (int j = 0; j < 32; j++) e[j] = fmaxf(e[j] + bias1[j], 0.f);

        #pragma unroll
        for (int n = 0; n < 64; n++) y[n] = bias2[n];
        #pragma unroll
        for (int j = 0; j < 32; j++) {
            const float ej = e[j];
            #pragma unroll
            for (int n4 = 0; n4 < 16; n4++) {
                const float4 wv = *(const float4*)&wyfcf[j * 64 + n4 * 4];
                y[n4 * 4 + 0] = fmaf(ej, wv.x, y[n4 * 4 + 0]);
                y[n4 * 4 + 1] = fmaf(ej, wv.y, y[n4 * 4 + 1]);
                y[n4 * 4 + 2] = fmaf(ej, wv.z, y[n4 * 4 + 2]);
                y[n4 * 4 + 3] = fmaf(ej, wv.w, y[n4 * 4 + 3]);
            }
        }
        #pragma unroll
        for (int n = 0; n < 64; n++) y[n] = fmaxf(y[n], 0.f);

        // ---- b1/v1 fp32 partials over this thread's k-range (a*64 .. a*64+63) ----
        const float* wbrow = Wb1 + (size_t)(a * 64) * 32;
        const float* wvrow = Wv1 + (size_t)(a * 64) * 32;
        #pragma unroll
        for (int eb = 0; eb < 4; eb++) {
            float pb[8], pv[8];
            #pragma unroll
            for (int j = 0; j < 8; j++) { pb[j] = 0.f; pv[j] = 0.f; }
            for (int n = 0; n < 64; n++) {
                const float yv = y[n];
                const float4 wb0 = *(const float4*)&wbrow[n * 32 + eb * 8];
                const float4 wb1v = *(const float4*)&wbrow[n * 32 + eb * 8 + 4];
                const float4 wv0 = *(const float4*)&wvrow[n * 32 + eb * 8];
                const float4 wv1v = *(const float4*)&wvrow[n * 32 + eb * 8 + 4];
                pb[0] = fmaf(yv, wb0.x, pb[0]); pb[1] = fmaf(yv, wb0.y, pb[1]);
                pb[2] = fmaf(yv, wb0.z, pb[2]); pb[3] = fmaf(yv, wb0.w, pb[3]);
                pb[4] = fmaf(yv, wb1v.x, pb[4]); pb[5] = fmaf(yv, wb1v.y, pb[5]);
                pb[6] = fmaf(yv, wb1v.z, pb[6]); pb[7] = fmaf(yv, wb1v.w, pb[7]);
                pv[0] = fmaf(yv, wv0.x, pv[0]); pv[1] = fmaf(yv, wv0.y, pv[1]);
                pv[2] = fmaf(yv, wv0.z, pv[2]); pv[3] = fmaf(yv, wv0.w, pv[3]);
                pv[4] = fmaf(yv, wv1v.x, pv[4]); pv[5] = fmaf(yv, wv1v.y, pv[5]);
                pv[6] = fmaf(yv, wv1v.z, pv[6]); pv[7] = fmaf(yv, wv1v.w, pv[7]);
            }
            #pragma unroll
            for (int j = 0; j < 8; j++) {
                atomicAdd(&b1s[s][eb * 8 + j], pb[j]);
                atomicAdd(&v1s[s][eb * 8 + j], pv[j]);
            }
        }
    }
    __syncthreads();   // S reads + atomics ordering point; R0 reusable

    // ---- Y split-scatter -> A3 hi/lo frags ----
    {
        const int s = tid >> 3, a = tid & 7;
        #pragma unroll
        for (int n = 0; n < 64; n++) {
            const int k3 = a * 64 + n;
            const float yv = y[n];
            const short yh = f2bf(yv);
            const short yl = f2bf(yv - bf2f(yh));
            const int si = ((s >> 4) * 16 + (k3 >> 5)) * 512
                         + (((k3 >> 3) & 3) * 16 + (s & 15)) * 8 + (k3 & 7);
            R0s[si] = yh;
            R0s[16384 + si] = yl;
        }
    }
    __syncthreads();

    // ---- GEMM3 (2-term split): Y[32x512] @ B3[512x512] (wide ntiles 0..31 only) ----
    f32x4 acc3[8][2];
    #pragma unroll
    for (int i = 0; i < 8; i++) {
        acc3[i][0] = (f32x4){0.f, 0.f, 0.f, 0.f};
        acc3[i][1] = (f32x4){0.f, 0.f, 0.f, 0.f};
    }
    for (int kt = 0; kt < 16; kt++) {
        const bfrag8 a0h = R0v[kt * 64 + lane];
        const bfrag8 a1h = R0v[(16 + kt) * 64 + lane];
        const bfrag8 a0l = R0v[2048 + kt * 64 + lane];
        const bfrag8 a1l = R0v[2048 + (16 + kt) * 64 + lane];
        bfrag8 bq[8];
        #pragma unroll
        for (int i = 0; i < 8; i++)
            bq[i] = wf_all[FRAG_G3 + ((w * 8 + i) * 16 + kt) * 64 + lane];
        #pragma unroll
        for (int i = 0; i < 8; i++) {
            acc3[i][0] = __builtin_amdgcn_mfma_f32_16x16x32_bf16(a0l, bq[i], acc3[i][0], 0, 0, 0);
            acc3[i][0] = __builtin_amdgcn_mfma_f32_16x16x32_bf16(a0h, bq[i], acc3[i][0], 0, 0, 0);
            acc3[i][1] = __builtin_amdgcn_mfma_f32_16x16x32_bf16(a1l, bq[i], acc3[i][1], 0, 0, 0);
            acc3[i][1] = __builtin_amdgcn_mfma_f32_16x16x32_bf16(a1h, bq[i], acc3[i][1], 0, 0, 0);
        }
    }
    __syncthreads();   // A3 reads done before A4/hf32 overwrite R0

    // ---- GEMM3 writer: h1 -> A4a hi/lo frags; hf -> hf32 fp32 ----
    #pragma unroll
    for (int i = 0; i < 8; i++) {
        const int ncol = (w * 8 + i) * 16 + nl;     // 0..511
        const float bs = bias3[ncol];
        #pragma unroll
        for (int mt = 0; mt < 2; mt++) {
            #pragma unroll
            for (int r = 0; r < 4; r++) {
                const int samp = mt * 16 + quad * 4 + r;
                const float h = fmaxf(acc3[i][mt][r] + bs, 0.f);
                if (ncol < 256) {
                    const short hh = f2bf(h);
                    const short hl = f2bf(h - bf2f(hh));
                    const int si = (mt * 8 + (ncol >> 5)) * 512
                                 + (((ncol >> 3) & 3) * 16 + (samp & 15)) * 8 + (ncol & 7);
                    R0s[si] = hh;
                    R0s[16384 + si] = hl;
                } else {
                    const int k4 = ncol - 256;
                    if (samp < 16) R0f[4096 + samp * 256 + k4] = h;
                    else           R0f[12288 + (samp - 16) * 256 + k4] = h;
                }
            }
        }
    }
    __syncthreads();

    // ---- GEMM4a (MFMA, 2-term): W1 = |H1@W1b + b1b| ; wf32 (fp32 VALU) ----
    f32x4 acc4[4][2];
    {
        #pragma unroll
        for (int i = 0; i < 4; i++) {
            acc4[i][0] = (f32x4){0.f, 0.f, 0.f, 0.f};
            acc4[i][1] = (f32x4){0.f, 0.f, 0.f, 0.f};
        }
        for (int kt = 0; kt < 8; kt++) {
            const bfrag8 a0h = R0v[kt * 64 + lane];
            const bfrag8 a1h = R0v[(8 + kt) * 64 + lane];
            const bfrag8 a0l = R0v[2048 + kt * 64 + lane];
            const bfrag8 a1l = R0v[2048 + (8 + kt) * 64 + lane];
            bfrag8 bq[4];
            #pragma unroll
            for (int i = 0; i < 4; i++)
                bq[i] = wf_all[FRAG_G4 + ((w * 4 + i) * 8 + kt) * 64 + lane];
            #pragma unroll
            for (int i = 0; i < 4; i++) {
                acc4[i][0] = __builtin_amdgcn_mfma_f32_16x16x32_bf16(a0l, bq[i], acc4[i][0], 0, 0, 0);
                acc4[i][0] = __builtin_amdgcn_mfma_f32_16x16x32_bf16(a0h, bq[i], acc4[i][0], 0, 0, 0);
                acc4[i][1] = __builtin_amdgcn_mfma_f32_16x16x32_bf16(a1l, bq[i], acc4[i][1], 0, 0, 0);
                acc4[i][1] = __builtin_amdgcn_mfma_f32_16x16x32_bf16(a1h, bq[i], acc4[i][1], 0, 0, 0);
            }
        }
        // wf = |HF @ Wfb + bfb| in exact fp32 from hf32
        const int samp = tid >> 3, cg = tid & 7;
        const float* hfrow = (samp < 16) ? &R0f[4096 + samp * 256]
                                         : &R0f[12288 + (samp - 16) * 256];
        float accw[4];
        #pragma unroll
        for (int j = 0; j < 4; j++) accw[j] = bfbs[cg * 4 + j];
        for (int k = 0; k < 256; k++) {
            const float hv = hfrow[k];
            const float4 wv = *(const float4*)&Wfb[k * 32 + cg * 4];
            accw[0] = fmaf(hv, wv.x, accw[0]);
            accw[1] = fmaf(hv, wv.y, accw[1]);
            accw[2] = fmaf(hv, wv.z, accw[2]);
            accw[3] = fmaf(hv, wv.w, accw[3]);
        }
        #pragma unroll
        for (int j = 0; j < 4; j++) wfs[samp][cg * 4 + j] = fabsf(accw[j]);
    }
    __syncthreads();   // A4a + hf32 reads done before w1 fp32 overwrites R0

    // ---- GEMM4a writer: w1 fp32 -> R0f[32][256] ----
    {
        #pragma unroll
        for (int i = 0; i < 4; i++) {
            const int ncol = (w * 4 + i) * 16 + nl;
            const float bs = bias4[ncol];
            #pragma unroll
            for (int mt = 0; mt < 2; mt++) {
                #pragma unroll
                for (int r = 0; r < 4; r++) {
                    const int samp = mt * 16 + quad * 4 + r;
                    R0f[samp * 256 + ncol] = fabsf(acc4[i][mt][r] + bs);
                }
            }
        }
    }
    __syncthreads();

    // ---- epilogue phase 1 ----
    {
        const int s = tid >> 3, l = tid & 7;
        #pragma unroll
        for (int ii = 0; ii < 4; ii++) {
            const int e = l * 4 + ii;
            float z = b1s[s][e];
            #pragma unroll
            for (int a = 0; a < 8; a++)
                z = fmaf(qs[s][a], R0f[s * 256 + a * 32 + e], z);
            const float h = (z > 0.f) ? z : (expf(z) - 1.f);
            const float d = (h < 0.f) ? expf(h) : 1.f;
            hid[s][e] = h;
            tpr[s][e] = d * wfs[s][e];
        }
    }
    __syncthreads();

    // ---- epilogue phase 2 ----
    {
        const int s = tid >> 3, a = tid & 7;
        const int b = base + s;
        float g = 0.f;
        #pragma unroll
        for (int e = 0; e < 32; e++)
            g = fmaf(R0f[s * 256 + a * 32 + e], tpr[s][e], g);
        out[BTOT + b * 8 + a] = g;
        if (a == 0) {
            float v = bv2[0];
            #pragma unroll
            for (int e = 0; e < 32; e++)
                v = fmaf(fmaxf(v1s[s][e], 0.f), wv2s[e], v);   // relu before Wv2 dot
            float qt = v;
            #pragma unroll
            for (int e = 0; e < 32; e++) qt = fmaf(hid[s][e], wfs[s][e], qt);
            out[b] = qt;
        }
    }
}

extern "C" void kernel_launch(void* const* d_in, const int* in_sizes, int n_in,
                              void* d_out, int out_size, void* d_ws, size_t ws_size,
                              hipStream_t stream) {
    const float* agent_qs = (const float*)d_in[0];
    const float* states   = (const float*)d_in[2];
    const float* W_tok = (const float*)d_in[4];
    const float* b_tok = (const float*)d_in[5];
    const float* W_yfc = (const float*)d_in[6];
    const float* b_yfc = (const float*)d_in[7];
    const float* W1a   = (const float*)d_in[8];
    const float* b1a   = (const float*)d_in[9];
    const float* W1b   = (const float*)d_in[10];
    const float* b1b   = (const float*)d_in[11];
    const float* Wfa   = (const float*)d_in[12];
    const float* bfa   = (const float*)d_in[13];
    const float* Wfb   = (const float*)d_in[14];
    const float* bfb   = (const float*)d_in[15];
    const float* Wb1   = (const float*)d_in[16];
    const float* bb1   = (const float*)d_in[17];
    const float* Wv1   = (const float*)d_in[18];
    const float* bv1   = (const float*)d_in[19];
    const float* Wv2   = (const float*)d_in[20];
    const float* bv2   = (const float*)d_in[21];
    float* out = (float*)d_out;
    bfrag8* wsf = (bfrag8*)d_ws;

    xmix_prep<<<180, 256, 0, stream>>>(W1a, W1b, Wfa, Wfb, Wb1, Wv1, wsf);
    xmix_main<<<NBLK, 256, 0, stream>>>(agent_qs, states, W_tok, b_tok,
                                        W_yfc, b_yfc, b1a, b1b, bfa, bfb,
                                        bb1, bv1, Wb1, Wv1, Wfb, Wv2, bv2,
                                        wsf, out);
}